// Round 1
// baseline (2185.262 us; speedup 1.0000x reference)
//
#include <hip/hip_runtime.h>

// Problem constants
//   B=4, C=16, G=8, KK=9
//   Level dims: L1 256x256 (pad1 conv), L2 254x254, L3 252x252

__global__ __launch_bounds__(256) void conv1_kernel(
    const float* __restrict__ in, const float* __restrict__ w,
    const float* __restrict__ bias, float* __restrict__ out)
{
    const int H = 256, W = 256;
    __shared__ float sIn[3][18][18];
    const int tx = threadIdx.x, ty = threadIdx.y;
    const int tid = ty * 16 + tx;
    const int bx = blockIdx.x, by = blockIdx.y, bb = blockIdx.z;
    const int x0 = bx * 16 - 1, y0 = by * 16 - 1;

    for (int idx = tid; idx < 3 * 18 * 18; idx += 256) {
        int c = idx / 324, rem = idx % 324, r = rem / 18, col = rem % 18;
        int gy = y0 + r, gx = x0 + col;
        float v = 0.f;
        if (gy >= 0 && gy < H && gx >= 0 && gx < W)
            v = in[((bb * 3 + c) * H + gy) * W + gx];
        sIn[c][r][col] = v;
    }
    __syncthreads();

    const int y = by * 16 + ty, x = bx * 16 + tx;  // grid exactly covers 256
    float acc[16];
#pragma unroll
    for (int o = 0; o < 16; o++) acc[o] = bias[o];
#pragma unroll
    for (int ci = 0; ci < 3; ci++) {
        float xv[9];
#pragma unroll
        for (int r = 0; r < 3; r++)
#pragma unroll
            for (int c = 0; c < 3; c++)
                xv[r * 3 + c] = sIn[ci][ty + r][tx + c];
#pragma unroll
        for (int o = 0; o < 16; o++) {
            const float* wp = w + (o * 3 + ci) * 9;
#pragma unroll
            for (int u = 0; u < 9; u++) acc[o] += wp[u] * xv[u];
        }
    }
#pragma unroll
    for (int o = 0; o < 16; o++)
        out[((size_t)(bb * 16 + o) * H + y) * W + x] = fmaxf(acc[o], 0.f);
}

// Cin=16 -> Cout=16, 3x3, pad 0, relu.  Hout = Hin-2.
__global__ __launch_bounds__(256) void conv16_kernel(
    const float* __restrict__ in, const float* __restrict__ w,
    const float* __restrict__ bias, float* __restrict__ out,
    int Hin, int Win)
{
    const int Hout = Hin - 2, Wout = Win - 2;
    __shared__ float sIn[16][18][18];
    const int tx = threadIdx.x, ty = threadIdx.y;
    const int tid = ty * 16 + tx;
    const int bx = blockIdx.x, by = blockIdx.y, bb = blockIdx.z;
    const int x0 = bx * 16, y0 = by * 16;  // pad 0

    for (int idx = tid; idx < 16 * 18 * 18; idx += 256) {
        int c = idx / 324, rem = idx % 324, r = rem / 18, col = rem % 18;
        int gy = y0 + r, gx = x0 + col;
        float v = 0.f;
        if (gy < Hin && gx < Win)
            v = in[((size_t)(bb * 16 + c) * Hin + gy) * Win + gx];
        sIn[c][r][col] = v;
    }
    __syncthreads();

    const int yr = by * 16 + ty, xr = bx * 16 + tx;
    const int y = min(yr, Hout - 1), x = min(xr, Wout - 1);  // keep CF uniform
    const int tyl = y - by * 16, txl = x - bx * 16;

    float acc[16];
#pragma unroll
    for (int o = 0; o < 16; o++) acc[o] = bias[o];
    for (int ci = 0; ci < 16; ci++) {
        float xv[9];
#pragma unroll
        for (int r = 0; r < 3; r++)
#pragma unroll
            for (int c = 0; c < 3; c++)
                xv[r * 3 + c] = sIn[ci][tyl + r][txl + c];
#pragma unroll
        for (int o = 0; o < 16; o++) {
            const float* wp = w + (o * 16 + ci) * 9;
#pragma unroll
            for (int u = 0; u < 9; u++) acc[o] += wp[u] * xv[u];
        }
    }
    if (yr < Hout && xr < Wout) {
#pragma unroll
        for (int o = 0; o < 16; o++)
            out[((size_t)(bb * 16 + o) * Hout + yr) * Wout + xr] = fmaxf(acc[o], 0.f);
    }
}

// Fused: offset conv (concat(ref,unr) 32ch -> 144ch, 3x3 pad1, relu)
//        + deformable conv (sample unr_f, groups=8, Cg=2, einsum with dcn_w).
// One thread per output pixel; computes all 144 offsets k-slice by k-slice.
__global__ __launch_bounds__(256) void offdef_kernel(
    const float* __restrict__ ref_f, const float* __restrict__ unr_f,
    const float* __restrict__ off_w, const float* __restrict__ off_b,
    const float* __restrict__ dcn_w, const float* __restrict__ dcn_b,
    float* __restrict__ out, int H, int W)
{
    __shared__ float sIn[32][18][18];
    const int tx = threadIdx.x, ty = threadIdx.y;
    const int tid = ty * 16 + tx;
    const int bx = blockIdx.x, by = blockIdx.y, bb = blockIdx.z;
    const int x0 = bx * 16 - 1, y0 = by * 16 - 1;

    for (int idx = tid; idx < 32 * 324; idx += 256) {
        int c = idx / 324, rem = idx % 324, r = rem / 18, col = rem % 18;
        int gy = y0 + r, gx = x0 + col;
        float v = 0.f;
        if (gy >= 0 && gy < H && gx >= 0 && gx < W) {
            const float* src = (c < 16) ? ref_f : unr_f;
            v = src[((size_t)(bb * 16 + (c & 15)) * H + gy) * W + gx];
        }
        sIn[c][r][col] = v;
    }
    __syncthreads();

    const int yr = by * 16 + ty, xr = bx * 16 + tx;
    const int y = min(yr, H - 1), x = min(xr, W - 1);  // uniform CF for scalar loads
    const int tyl = y - by * 16, txl = x - bx * 16;

    float pout[16];
#pragma unroll
    for (int o = 0; o < 16; o++) pout[o] = dcn_b[o];

    const float* ub = unr_f + (size_t)bb * 16 * H * W;

    for (int k = 0; k < 9; k++) {
        // ---- offset conv: 16 channels for this k (8 groups x {oy,ox}) ----
        float acc[16];
#pragma unroll
        for (int t = 0; t < 16; t++) {
            int g = t >> 1, d = t & 1;
            acc[t] = off_b[g * 18 + k * 2 + d];
        }
        for (int ci = 0; ci < 32; ci++) {
            float xv[9];
#pragma unroll
            for (int r = 0; r < 3; r++)
#pragma unroll
                for (int c = 0; c < 3; c++)
                    xv[r * 3 + c] = sIn[ci][tyl + r][txl + c];
#pragma unroll
            for (int t = 0; t < 16; t++) {
                int g = t >> 1, d = t & 1;
                const float* wp = off_w + ((size_t)((g * 18 + k * 2 + d) * 32 + ci)) * 9;
#pragma unroll
                for (int u = 0; u < 9; u++) acc[t] += wp[u] * xv[u];
            }
        }

        // ---- deformable sampling for this k ----
        const float fy = (float)y - 1.0f + (float)(k / 3);
        const float fx = (float)x - 1.0f + (float)(k % 3);
#pragma unroll
        for (int g = 0; g < 8; g++) {
            float oy = fmaxf(acc[g * 2 + 0], 0.f);  // relu on offset map
            float ox = fmaxf(acc[g * 2 + 1], 0.f);
            float ys = fy + oy, xs = fx + ox;
            float y0f = floorf(ys), x0f = floorf(xs);
            float dy = ys - y0f, dx = xs - x0f;
            int iy0 = (int)y0f, ix0 = (int)x0f;
            int iy1 = iy0 + 1, ix1 = ix0 + 1;
            float vy0 = (iy0 >= 0 && iy0 < H) ? 1.f : 0.f;
            float vy1 = (iy1 >= 0 && iy1 < H) ? 1.f : 0.f;
            float vx0 = (ix0 >= 0 && ix0 < W) ? 1.f : 0.f;
            float vx1 = (ix1 >= 0 && ix1 < W) ? 1.f : 0.f;
            int cy0 = min(max(iy0, 0), H - 1), cy1 = min(max(iy1, 0), H - 1);
            int cx0 = min(max(ix0, 0), W - 1), cx1 = min(max(ix1, 0), W - 1);
            float w00 = (1.f - dy) * (1.f - dx) * vy0 * vx0;
            float w01 = (1.f - dy) * dx * vy0 * vx1;
            float w10 = dy * (1.f - dx) * vy1 * vx0;
            float w11 = dy * dx * vy1 * vx1;
#pragma unroll
            for (int cg = 0; cg < 2; cg++) {
                const float* bptr = ub + (size_t)(2 * g + cg) * H * W;
                float v = w00 * bptr[cy0 * W + cx0] + w01 * bptr[cy0 * W + cx1]
                        + w10 * bptr[cy1 * W + cx0] + w11 * bptr[cy1 * W + cx1];
#pragma unroll
                for (int o = 0; o < 16; o++)
                    pout[o] += dcn_w[(o * 16 + 2 * g + cg) * 9 + k] * v;
            }
        }
    }

    if (yr < H && xr < W) {
#pragma unroll
        for (int o = 0; o < 16; o++)
            out[((size_t)(bb * 16 + o) * H + yr) * W + xr] = pout[o];
    }
}

extern "C" void kernel_launch(void* const* d_in, const int* in_sizes, int n_in,
                              void* d_out, int out_size, void* d_ws, size_t ws_size,
                              hipStream_t stream) {
    (void)in_sizes; (void)n_in; (void)out_size; (void)ws_size;
    const float* ref = (const float*)d_in[0];
    const float* unr = (const float*)d_in[1];
    const float* c1w = (const float*)d_in[2];  const float* c1b = (const float*)d_in[3];
    const float* c2w = (const float*)d_in[4];  const float* c2b = (const float*)d_in[5];
    const float* c3w = (const float*)d_in[6];  const float* c3b = (const float*)d_in[7];
    const float* o1w = (const float*)d_in[8];  const float* o1b = (const float*)d_in[9];
    const float* o2w = (const float*)d_in[10]; const float* o2b = (const float*)d_in[11];
    const float* o3w = (const float*)d_in[12]; const float* o3b = (const float*)d_in[13];
    const float* dw  = (const float*)d_in[14]; const float* db  = (const float*)d_in[15];

    float* out0 = (float*)d_out;                    // 4*16*256*256
    float* out1 = out0 + (size_t)4 * 16 * 256 * 256; // 4*16*254*254
    float* out2 = out1 + (size_t)4 * 16 * 254 * 254; // 4*16*252*252

    float* fA = (float*)d_ws;                        // cap 4*16*256*256
    float* fB = fA + (size_t)4 * 16 * 256 * 256;
    float* fC = fB + (size_t)4 * 16 * 256 * 256;     // 4*16*254*254
    float* fD = fC + (size_t)4 * 16 * 254 * 254;

    dim3 blk(16, 16);

    // Level 1 features
    conv1_kernel<<<dim3(16, 16, 4), blk, 0, stream>>>(ref, c1w, c1b, fA);
    conv1_kernel<<<dim3(16, 16, 4), blk, 0, stream>>>(unr, c1w, c1b, fB);
    // Level 1 align
    offdef_kernel<<<dim3(16, 16, 4), blk, 0, stream>>>(fA, fB, o1w, o1b, dw, db, out0, 256, 256);
    // Level 2 features (ceil(254/16)=16)
    conv16_kernel<<<dim3(16, 16, 4), blk, 0, stream>>>(fA, c2w, c2b, fC, 256, 256);
    conv16_kernel<<<dim3(16, 16, 4), blk, 0, stream>>>(fB, c2w, c2b, fD, 256, 256);
    offdef_kernel<<<dim3(16, 16, 4), blk, 0, stream>>>(fC, fD, o2w, o2b, dw, db, out1, 254, 254);
    // Level 3 features (reuse fA/fB; ceil(252/16)=16)
    conv16_kernel<<<dim3(16, 16, 4), blk, 0, stream>>>(fC, c3w, c3b, fA, 254, 254);
    conv16_kernel<<<dim3(16, 16, 4), blk, 0, stream>>>(fD, c3w, c3b, fB, 254, 254);
    offdef_kernel<<<dim3(16, 16, 4), blk, 0, stream>>>(fA, fB, o3w, o3b, dw, db, out2, 252, 252);
}